// Round 3
// baseline (48480.832 us; speedup 1.0000x reference)
//
#include <hip/hip_runtime.h>
#include <math.h>

#define B_   256
#define E_   304
#define H_   304
#define G3_  912
#define T_   512
#define P_   68
#define PD   67      // decoder output positions
#define D_   61
#define KCW  76      // k-chunk per wave (304/4)
#define NCB  8       // col-blocks (group size)
#define NBG  32      // batch groups
#define RB   8       // rows per block
#define CBH  38      // h-cols per block
#define GC   114     // gate-cols per block (3*38)
#define NSTEP (T_ + PD)

typedef unsigned long long ull;

// red[m][kc][cc][rr] m: 0=gi,1=gh ; padded inner dim 9 (stride 9 words, odd -> bank spread)
#define RED(m, kc, cc, rr) lds_red[(((m)*4 + (kc))*GC + (cc))*9 + (rr)]

__device__ __forceinline__ void dot4(float& a, const float4& v, const float4& m) {
    a += v.x * m.x; a += v.y * m.y; a += v.z * m.z; a += v.w * m.w;
}

// ---------------------------------------------------------------------------
// Persistent GRU: runs all 512 encoder + 67 decoder steps in one launch.
// Grid (NCB, NBG) = (8,32) blocks of 256 threads, 1 block/CU (co-resident).
// Block (cb,bg): batch rows r0=bg*8..+7, h-cols c0=cb*38..+37 (114 gate-cols).
// Thread (kc=wave 0..3, lane 0..56): holds Wih+Whh for gate-cols {lane, lane+57},
// k-slice kc*76..+75 in VGPRs (304 regs), persistent across all steps.
// Exchange of h between the 8 col-blocks of a group: agent-scope atomics into
// double-buffered hbuf + per-group counter barrier.
// ---------------------------------------------------------------------------
__global__ __launch_bounds__(256, 1) void gru_persist(
    const float* __restrict__ input,   // [B][T][E]
    const int*   __restrict__ target,  // [B][P]
    const float* __restrict__ emb,     // [D][E]
    const float* __restrict__ eWih, const float* __restrict__ eWhh,
    const float* __restrict__ ebih, const float* __restrict__ ebhh,
    const float* __restrict__ dWih, const float* __restrict__ dWhh,
    const float* __restrict__ dbih, const float* __restrict__ dbhh,
    float* hbuf,                       // [2][B*H]
    float* __restrict__ dec_outs,      // [(b*PD+p)*H]
    int* ctr)                          // [NBG*32]
{
    __shared__ float xs[RB][H_];
    __shared__ float hs[RB][H_];
    __shared__ float lds_red[2 * 4 * GC * 9];
    __shared__ float bi_l[GC], bh_l[GC];

    const int tid  = threadIdx.x;
    const int cb   = blockIdx.x;       // 0..7
    const int bg   = blockIdx.y;       // 0..31
    const int r0   = bg * RB;
    const int c0h  = cb * CBH;
    const int kc   = tid >> 6;         // wave id
    const int lane = tid & 63;
    const bool act = lane < 57;
    int* ctrp = ctr + bg * 32;

    float4 wi[2][19], wh[2][19];

    // ---- weight/bias load (phase = 0 encoder, 1 decoder) ----
    auto load_wb = [&](const float* Wih, const float* Whh,
                       const float* bih, const float* bhh) {
        if (act) {
            #pragma unroll
            for (int t = 0; t < 2; ++t) {
                int cc = lane + t * 57;
                int g = cc / CBH, j = cc - (cc / CBH) * CBH;
                const float* pi = Wih + (size_t)(g * H_ + c0h + j) * H_ + kc * KCW;
                const float* ph = Whh + (size_t)(g * H_ + c0h + j) * H_ + kc * KCW;
                #pragma unroll
                for (int q = 0; q < 19; ++q) {
                    wi[t][q] = *(const float4*)(pi + 4 * q);
                    wh[t][q] = *(const float4*)(ph + 4 * q);
                }
            }
        }
        if (tid < GC) {
            int g = tid / CBH, j = tid - (tid / CBH) * CBH;
            bi_l[tid] = bih[g * H_ + c0h + j];
            bh_l[tid] = bhh[g * H_ + c0h + j];
        }
    };

    load_wb(eWih, eWhh, ebih, ebhh);

    for (int s = 0; s < NSTEP; ++s) {
        const bool enc = (s < T_);
        const int p = s - T_;
        if (s == T_) load_wb(dWih, dWhh, dbih, dbhh);

        // ---- stage x rows ----
        if (enc) {
            for (int f = tid; f < RB * 76; f += 256) {
                int rr = f / 76, q = f - (f / 76) * 76;
                *(float4*)&xs[rr][4 * q] =
                    *(const float4*)(input + ((size_t)(r0 + rr) * T_ + s) * E_ + 4 * q);
            }
        } else {
            for (int f = tid; f < RB * 76; f += 256) {
                int rr = f / 76, q = f - (f / 76) * 76;
                int b = r0 + rr;
                int tok = (p == 0) ? 0 : target[b * P_ + p];
                *(float4*)&xs[rr][4 * q] =
                    *(const float4*)(emb + (size_t)tok * E_ + 4 * q);
            }
        }
        // ---- stage h rows (agent-scope coherent reads) ----
        if (s == 0) {
            for (int f = tid; f < RB * 76; f += 256) {
                int rr = f / 76, q = f - (f / 76) * 76;
                *(float4*)&hs[rr][4 * q] = make_float4(0.f, 0.f, 0.f, 0.f);
            }
        } else {
            ull* src = (ull*)(hbuf + (size_t)(s & 1) * (B_ * H_));
            for (int f = tid; f < RB * 152; f += 256) {
                int rr = f / 152, q = f - (f / 152) * 152;
                ull u = __hip_atomic_load(&src[(size_t)(r0 + rr) * 152 + q],
                                          __ATOMIC_RELAXED, __HIP_MEMORY_SCOPE_AGENT);
                ((ull*)&hs[rr][0])[q] = u;
            }
        }
        __syncthreads();

        // ---- main GEMMs: gi (x·Wih) and gh (h·Whh), weights in VGPRs ----
        if (act) {
            #pragma unroll 2
            for (int rr = 0; rr < RB; ++rr) {
                float ai[2][2] = {{0.f, 0.f}, {0.f, 0.f}};
                float ah[2][2] = {{0.f, 0.f}, {0.f, 0.f}};
                #pragma unroll
                for (int q = 0; q < 19; ++q) {
                    float4 xv = *(const float4*)&xs[rr][kc * KCW + 4 * q];
                    float4 hv = *(const float4*)&hs[rr][kc * KCW + 4 * q];
                    dot4(ai[0][q & 1], xv, wi[0][q]);
                    dot4(ai[1][q & 1], xv, wi[1][q]);
                    dot4(ah[0][q & 1], hv, wh[0][q]);
                    dot4(ah[1][q & 1], hv, wh[1][q]);
                }
                RED(0, kc, lane,      rr) = ai[0][0] + ai[0][1];
                RED(0, kc, lane + 57, rr) = ai[1][0] + ai[1][1];
                RED(1, kc, lane,      rr) = ah[0][0] + ah[0][1];
                RED(1, kc, lane + 57, rr) = ah[1][0] + ah[1][1];
            }
        }
        __syncthreads();

        // ---- gates + h write ----
        float* hdst = hbuf + (size_t)((s + 1) & 1) * (B_ * H_);
        for (int o = tid; o < RB * CBH; o += 256) {
            int rr = o / CBH, j = o - (o / CBH) * CBH;
            int col = c0h + j;
            float Gi[3], Gh[3];
            #pragma unroll
            for (int g = 0; g < 3; ++g) {
                int cc = g * CBH + j;
                Gi[g] = RED(0, 0, cc, rr) + RED(0, 1, cc, rr) +
                        RED(0, 2, cc, rr) + RED(0, 3, cc, rr) + bi_l[cc];
                Gh[g] = RED(1, 0, cc, rr) + RED(1, 1, cc, rr) +
                        RED(1, 2, cc, rr) + RED(1, 3, cc, rr) + bh_l[cc];
            }
            float rg = 1.f / (1.f + expf(-(Gi[0] + Gh[0])));
            float zg = 1.f / (1.f + expf(-(Gi[1] + Gh[1])));
            float ng = tanhf(Gi[2] + rg * Gh[2]);
            float hnew = (1.f - zg) * ng + zg * hs[rr][col];
            __hip_atomic_store(&hdst[(size_t)(r0 + rr) * H_ + col], hnew,
                               __ATOMIC_RELAXED, __HIP_MEMORY_SCOPE_AGENT);
            if (!enc)
                dec_outs[((size_t)(r0 + rr) * PD + p) * H_ + col] = hnew;
        }
        __syncthreads();   // all stores drained (vmcnt) before arrival

        // ---- group barrier: the 8 col-blocks of this batch group ----
        if (tid == 0) {
            __hip_atomic_fetch_add(ctrp, 1, __ATOMIC_ACQ_REL, __HIP_MEMORY_SCOPE_AGENT);
            int tgt = NCB * (s + 1);
            while (__hip_atomic_load(ctrp, __ATOMIC_ACQUIRE,
                                     __HIP_MEMORY_SCOPE_AGENT) < tgt)
                __builtin_amdgcn_s_sleep(1);
        }
        __syncthreads();
    }
}

// ---------------------------------------------------------------------------
// logits -> softmax -> (softmax_cal, target_cal, asr_outputs)
// One wave per output row (r = b*67 + p); 4 rows per block.
// ---------------------------------------------------------------------------
__global__ __launch_bounds__(256) void logits_softmax(
    const float* __restrict__ dec_outs,   // [B*PD][H]
    const float* __restrict__ linW,       // [61][304]
    const float* __restrict__ linb,       // [61]
    const int* __restrict__ target,       // [B][P][1]
    float* __restrict__ out)
{
    __shared__ float wsm[H_][64];   // transposed W
    __shared__ float rs[4][H_];
    const int tid = threadIdx.x;
    const int wv = tid >> 6, l = tid & 63;

    for (int f = tid; f < H_ * 64; f += 256) {
        int k = f >> 6, ll = f & 63;
        wsm[k][ll] = (ll < D_) ? linW[(size_t)ll * H_ + k] : 0.f;
    }
    const int r = blockIdx.x * 4 + wv;
    const float* rowp = dec_outs + (size_t)r * H_;
    for (int k = l; k < H_; k += 64) rs[wv][k] = rowp[k];
    __syncthreads();

    float acc = -1e30f;
    if (l < D_) {
        acc = linb[l];
        #pragma unroll 4
        for (int k = 0; k < H_; ++k) acc += rs[wv][k] * wsm[k][l];
    }
    float m = acc;
    for (int off = 32; off; off >>= 1) m = fmaxf(m, __shfl_xor(m, off));
    float e = (l < D_) ? expf(acc - m) : 0.f;
    float s = e;
    for (int off = 32; off; off >>= 1) s += __shfl_xor(s, off);
    float av = acc; int ai = l;
    for (int off = 32; off; off >>= 1) {
        float ov = __shfl_xor(av, off);
        int oi = __shfl_xor(ai, off);
        if (ov > av || (ov == av && oi < ai)) { av = ov; ai = oi; }
    }
    const int b = r / PD, p = r - (r / PD) * PD;
    const size_t OFF1 = (size_t)B_ * PD * D_;
    const size_t OFF2 = OFF1 + (size_t)B_ * PD;
    if (l < D_)        out[(size_t)r * D_ + l] = e / s;
    else if (l == D_)  out[OFF1 + r] = (float)target[b * P_ + p + 1];
    else if (l == D_ + 1) out[OFF2 + r] = (float)ai;
}

// ---------------------------------------------------------------------------
extern "C" void kernel_launch(void* const* d_in, const int* in_sizes, int n_in,
                              void* d_out, int out_size, void* d_ws, size_t ws_size,
                              hipStream_t stream)
{
    const float* input  = (const float*)d_in[0];
    const int*   target = (const int*)d_in[1];
    const float* eWih = (const float*)d_in[3];
    const float* eWhh = (const float*)d_in[4];
    const float* ebih = (const float*)d_in[5];
    const float* ebhh = (const float*)d_in[6];
    const float* emb  = (const float*)d_in[7];
    const float* dWih = (const float*)d_in[8];
    const float* dWhh = (const float*)d_in[9];
    const float* dbih = (const float*)d_in[10];
    const float* dbhh = (const float*)d_in[11];
    const float* linW = (const float*)d_in[12];
    const float* linb = (const float*)d_in[13];
    float* out = (float*)d_out;

    int*   ctr      = (int*)d_ws;                    // NBG*32 ints (4 KB)
    float* hbuf     = (float*)d_ws + 1024;           // 2 * B*H
    float* dec_outs = hbuf + 2 * (size_t)B_ * H_;    // B*PD*H

    (void)hipMemsetAsync(ctr, 0, 1024 * sizeof(int), stream);

    gru_persist<<<dim3(NCB, NBG), 256, 0, stream>>>(
        input, target, emb,
        eWih, eWhh, ebih, ebhh,
        dWih, dWhh, dbih, dbhh,
        hbuf, dec_outs, ctr);

    logits_softmax<<<dim3(B_ * PD / 4), 256, 0, stream>>>(
        dec_outs, linW, linb, target, out);
}

// Round 4
// 10823.605 us; speedup vs baseline: 4.4792x; 4.4792x over previous
//
#include <hip/hip_runtime.h>
#include <math.h>

#define B_   256
#define E_   304
#define H_   304
#define T_   512
#define P_   68
#define PD   67      // decoder output positions
#define D_   61
#define NCB  16      // col-blocks per batch group
#define NBG  16      // batch groups
#define RB   16      // rows (batch) per block
#define CBH  19      // h-cols per block
#define GC   57      // gate-cols per block (3*19)
#define KCW  76      // k-chunk per wave (304/4)
#define NSTEP (T_ + PD)
#define HW   152     // ull words per h/x row (304 floats)
#define BLK_ULL (RB * HW)   // 2432

typedef unsigned long long ull;

// per-kc partials: red[m][kc][cc][rr], inner pad 17 (odd stride -> bank spread)
#define RED(m, kc, cc, rr) lds_red[(((m)*4 + (kc))*GC + (cc))*17 + (rr)]

__device__ __forceinline__ void dot4(float& a, const float4& v, const float4& m) {
    a += v.x * m.x; a += v.y * m.y; a += v.z * m.z; a += v.w * m.w;
}

// ---------------------------------------------------------------------------
// Persistent GRU: all 512 encoder + 67 decoder steps in one launch.
// Grid (NCB, NBG) = (16,16), 256 threads, 1 block/CU, co-resident.
// Block (cb,bg): rows r0=bg*16..+15, h-cols c0h=cb*19..+18 (57 gate-cols).
// Thread (kc=wave, lane<57): holds Wih+Whh k-chunk for ONE gate-col:
// 2*19 float4 = 152 VGPRs (fits the 256 arch-VGPR cap -> no spill).
// Cross-block h exchange: relaxed agent-scope atomics via MALL, double-
// buffered hbuf; per-group counter barrier (relaxed; __syncthreads drains
// vmcnt before the add, so no release/acquire L2 flushes needed).
// ---------------------------------------------------------------------------
__global__ __launch_bounds__(256, 1) void gru_persist(
    const float* __restrict__ input,   // [B][T][E]
    const int*   __restrict__ target,  // [B][P]
    const float* __restrict__ emb,     // [D][E]
    const float* __restrict__ eWih, const float* __restrict__ eWhh,
    const float* __restrict__ ebih, const float* __restrict__ ebhh,
    const float* __restrict__ dWih, const float* __restrict__ dWhh,
    const float* __restrict__ dbih, const float* __restrict__ dbhh,
    float* hbuf,                       // [2][B*H]
    float* __restrict__ dec_outs,      // [(b*PD+p)*H]
    int* ctr)                          // [NBG*32]
{
    __shared__ float xs[RB][H_];
    __shared__ float hs[RB][H_];
    __shared__ float lds_red[2 * 4 * GC * 17];
    __shared__ float bi_l[GC], bh_l[GC];
    __shared__ int   toks_l[RB];

    const int tid  = threadIdx.x;
    const int cb   = blockIdx.x;       // 0..15
    const int bg   = blockIdx.y;       // 0..15
    const int r0   = bg * RB;
    const int c0h  = cb * CBH;
    const int kc   = tid >> 6;         // wave id = k-chunk
    const int lane = tid & 63;
    const bool act = lane < GC;
    int* ctrp = ctr + bg * 32;

    float4 wi[19], wh[19];

    auto load_wb = [&](const float* Wih, const float* Whh,
                       const float* bih, const float* bhh) {
        if (act) {
            int g = lane / CBH, j = lane - (lane / CBH) * CBH;
            const float* pi = Wih + (size_t)(g * H_ + c0h + j) * E_ + kc * KCW;
            const float* ph = Whh + (size_t)(g * H_ + c0h + j) * H_ + kc * KCW;
            #pragma unroll
            for (int q = 0; q < 19; ++q) {
                wi[q] = *(const float4*)(pi + 4 * q);
                wh[q] = *(const float4*)(ph + 4 * q);
            }
        }
        if (tid < GC) {
            int g = tid / CBH, j = tid - (tid / CBH) * CBH;
            bi_l[tid] = bih[g * H_ + c0h + j];
            bh_l[tid] = bhh[g * H_ + c0h + j];
        }
    };

    load_wb(eWih, eWhh, ebih, ebhh);

    // ---- prologue: stage x(0) into xs ----
    {
        const ull* xin = (const ull*)input;
        #pragma unroll
        for (int i = 0; i < 10; ++i) {
            int f = tid + 256 * i;
            if (i < 9 || f < BLK_ULL) {
                int rr = f / HW, q = f - (f / HW) * HW;
                ((ull*)xs)[f] = xin[(size_t)(r0 + rr) * T_ * HW + q];
            }
        }
    }
    __syncthreads();

    for (int s = 0; s < NSTEP; ++s) {
        const bool enc = (s < T_);
        if (s == T_) load_wb(dWih, dWhh, dbih, dbhh);
        const int p1 = s + 1 - T_;     // decoder position of x(s+1)

        // ==== phase A/B: issue h loads early; gi GEMM (no h dep); hs write ====
        {
            ull hreg[10];
            if (s > 0) {
                const ull* hsrc = (const ull*)(hbuf + (size_t)(s & 1) * (B_ * H_))
                                  + (size_t)r0 * HW;
                #pragma unroll
                for (int i = 0; i < 10; ++i) {
                    int f = tid + 256 * i;
                    if (i < 9 || f < BLK_ULL)
                        hreg[i] = __hip_atomic_load(hsrc + f, __ATOMIC_RELAXED,
                                                    __HIP_MEMORY_SCOPE_AGENT);
                }
            }
            // next-step decoder tokens
            if (p1 > 0 && s + 1 < NSTEP && tid < RB)
                toks_l[tid] = target[(r0 + tid) * P_ + p1];

            // gi GEMM: x(s) . Wih
            if (act) {
                #pragma unroll 4
                for (int rr = 0; rr < RB; ++rr) {
                    float a0 = 0.f, a1 = 0.f;
                    #pragma unroll
                    for (int q = 0; q < 19; ++q) {
                        float4 xv = *(const float4*)&xs[rr][kc * KCW + 4 * q];
                        if (q & 1) dot4(a1, xv, wi[q]); else dot4(a0, xv, wi[q]);
                    }
                    RED(0, kc, lane, rr) = a0 + a1;
                }
            }
            // write h into hs
            if (s > 0) {
                ull* hd = (ull*)hs;
                #pragma unroll
                for (int i = 0; i < 10; ++i) {
                    int f = tid + 256 * i;
                    if (i < 9 || f < BLK_ULL) hd[f] = hreg[i];
                }
            } else {
                for (int f = tid; f < BLK_ULL; f += 256) ((ull*)hs)[f] = 0ull;
            }
        }
        __syncthreads();   // #1: hs + red[0] complete

        // ==== phase C: prefetch x(s+1) into regs; gh GEMM ====
        ull xr[10];
        const bool havex = (s + 1 < NSTEP);
        if (havex) {
            if (s + 1 < T_) {
                const ull* xin = (const ull*)input;
                #pragma unroll
                for (int i = 0; i < 10; ++i) {
                    int f = tid + 256 * i;
                    if (i < 9 || f < BLK_ULL) {
                        int rr = f / HW, q = f - (f / HW) * HW;
                        xr[i] = xin[((size_t)(r0 + rr) * T_ + (s + 1)) * HW + q];
                    }
                }
            } else {
                const ull* eb = (const ull*)emb;
                #pragma unroll
                for (int i = 0; i < 10; ++i) {
                    int f = tid + 256 * i;
                    if (i < 9 || f < BLK_ULL) {
                        int rr = f / HW, q = f - (f / HW) * HW;
                        int tok = (p1 == 0) ? 0 : toks_l[rr];
                        xr[i] = eb[(size_t)tok * HW + q];
                    }
                }
            }
        }
        // gh GEMM: h(s) . Whh
        if (act) {
            #pragma unroll 4
            for (int rr = 0; rr < RB; ++rr) {
                float a0 = 0.f, a1 = 0.f;
                #pragma unroll
                for (int q = 0; q < 19; ++q) {
                    float4 hv = *(const float4*)&hs[rr][kc * KCW + 4 * q];
                    if (q & 1) dot4(a1, hv, wh[q]); else dot4(a0, hv, wh[q]);
                }
                RED(1, kc, lane, rr) = a0 + a1;
            }
        }
        __syncthreads();   // #2: red complete

        // ==== phase D: gates, h store, dec store, xs refresh ====
        float* hdst = hbuf + (size_t)((s + 1) & 1) * (B_ * H_);
        for (int o = tid; o < RB * CBH; o += 256) {
            int rr = o / CBH, j = o - (o / CBH) * CBH;
            int col = c0h + j;
            float Gi[3], Gh[3];
            #pragma unroll
            for (int g = 0; g < 3; ++g) {
                int cc = g * CBH + j;
                Gi[g] = RED(0, 0, cc, rr) + RED(0, 1, cc, rr) +
                        RED(0, 2, cc, rr) + RED(0, 3, cc, rr) + bi_l[cc];
                Gh[g] = RED(1, 0, cc, rr) + RED(1, 1, cc, rr) +
                        RED(1, 2, cc, rr) + RED(1, 3, cc, rr) + bh_l[cc];
            }
            float rg = 1.f / (1.f + expf(-(Gi[0] + Gh[0])));
            float zg = 1.f / (1.f + expf(-(Gi[1] + Gh[1])));
            float ng = tanhf(Gi[2] + rg * Gh[2]);
            float hnew = (1.f - zg) * ng + zg * hs[rr][col];
            __hip_atomic_store(&hdst[(size_t)(r0 + rr) * H_ + col], hnew,
                               __ATOMIC_RELAXED, __HIP_MEMORY_SCOPE_AGENT);
            if (!enc)
                dec_outs[((size_t)(r0 + rr) * PD + (s - T_)) * H_ + col] = hnew;
        }
        if (havex) {
            ull* xd = (ull*)xs;
            #pragma unroll
            for (int i = 0; i < 10; ++i) {
                int f = tid + 256 * i;
                if (i < 9 || f < BLK_ULL) xd[f] = xr[i];
            }
        }
        __syncthreads();   // #3: drains h stores (vmcnt) + xs writes

        // ==== group barrier (16 col-blocks of this batch group) ====
        if (s + 1 < NSTEP) {
            if (tid == 0) {
                __hip_atomic_fetch_add(ctrp, 1, __ATOMIC_RELAXED,
                                       __HIP_MEMORY_SCOPE_AGENT);
                int tgt = NCB * (s + 1);
                while (__hip_atomic_load(ctrp, __ATOMIC_RELAXED,
                                         __HIP_MEMORY_SCOPE_AGENT) < tgt)
                    __builtin_amdgcn_s_sleep(1);
            }
            __syncthreads();   // #4
        }
    }
}

// ---------------------------------------------------------------------------
// logits -> softmax -> (softmax_cal, target_cal, asr_outputs)
// One wave per output row (r = b*67 + p); 4 rows per block.
// ---------------------------------------------------------------------------
__global__ __launch_bounds__(256) void logits_softmax(
    const float* __restrict__ dec_outs,   // [B*PD][H]
    const float* __restrict__ linW,       // [61][304]
    const float* __restrict__ linb,       // [61]
    const int* __restrict__ target,       // [B][P][1]
    float* __restrict__ out)
{
    __shared__ float wsm[H_][64];   // transposed W
    __shared__ float rs[4][H_];
    const int tid = threadIdx.x;
    const int wv = tid >> 6, l = tid & 63;

    for (int f = tid; f < H_ * 64; f += 256) {
        int k = f >> 6, ll = f & 63;
        wsm[k][ll] = (ll < D_) ? linW[(size_t)ll * H_ + k] : 0.f;
    }
    const int r = blockIdx.x * 4 + wv;
    const float* rowp = dec_outs + (size_t)r * H_;
    for (int k = l; k < H_; k += 64) rs[wv][k] = rowp[k];
    __syncthreads();

    float acc = -1e30f;
    if (l < D_) {
        acc = linb[l];
        #pragma unroll 4
        for (int k = 0; k < H_; ++k) acc += rs[wv][k] * wsm[k][l];
    }
    float m = acc;
    for (int off = 32; off; off >>= 1) m = fmaxf(m, __shfl_xor(m, off));
    float e = (l < D_) ? expf(acc - m) : 0.f;
    float s = e;
    for (int off = 32; off; off >>= 1) s += __shfl_xor(s, off);
    float av = acc; int ai = l;
    for (int off = 32; off; off >>= 1) {
        float ov = __shfl_xor(av, off);
        int oi = __shfl_xor(ai, off);
        if (ov > av || (ov == av && oi < ai)) { av = ov; ai = oi; }
    }
    const int b = r / PD, p = r - (r / PD) * PD;
    const size_t OFF1 = (size_t)B_ * PD * D_;
    const size_t OFF2 = OFF1 + (size_t)B_ * PD;
    if (l < D_)        out[(size_t)r * D_ + l] = e / s;
    else if (l == D_)  out[OFF1 + r] = (float)target[b * P_ + p + 1];
    else if (l == D_ + 1) out[OFF2 + r] = (float)ai;
}

// ---------------------------------------------------------------------------
extern "C" void kernel_launch(void* const* d_in, const int* in_sizes, int n_in,
                              void* d_out, int out_size, void* d_ws, size_t ws_size,
                              hipStream_t stream)
{
    const float* input  = (const float*)d_in[0];
    const int*   target = (const int*)d_in[1];
    const float* eWih = (const float*)d_in[3];
    const float* eWhh = (const float*)d_in[4];
    const float* ebih = (const float*)d_in[5];
    const float* ebhh = (const float*)d_in[6];
    const float* emb  = (const float*)d_in[7];
    const float* dWih = (const float*)d_in[8];
    const float* dWhh = (const float*)d_in[9];
    const float* dbih = (const float*)d_in[10];
    const float* dbhh = (const float*)d_in[11];
    const float* linW = (const float*)d_in[12];
    const float* linb = (const float*)d_in[13];
    float* out = (float*)d_out;

    int*   ctr      = (int*)d_ws;                    // NBG*32 ints (2 KB)
    float* hbuf     = (float*)d_ws + 512;            // 2 * B*H
    float* dec_outs = hbuf + 2 * (size_t)B_ * H_;    // B*PD*H

    (void)hipMemsetAsync(ctr, 0, 512 * sizeof(int), stream);

    gru_persist<<<dim3(NCB, NBG), 256, 0, stream>>>(
        input, target, emb,
        eWih, eWhh, ebih, ebhh,
        dWih, dWhh, dbih, dbhh,
        hbuf, dec_outs, ctr);

    logits_softmax<<<dim3(B_ * PD / 4), 256, 0, stream>>>(
        dec_outs, linW, linb, target, out);
}

// Round 5
// 6501.122 us; speedup vs baseline: 7.4573x; 1.6649x over previous
//
#include <hip/hip_runtime.h>
#include <math.h>

#define B_   256
#define E_   304
#define H_   304
#define T_   512
#define P_   68
#define PD   67      // decoder output positions
#define D_   61
#define NCB  16      // col-blocks per batch group
#define NBG  32      // batch groups
#define RB   8       // rows (batch) per block
#define CBH  19      // h-cols per block
#define GC   57      // gate-cols per block (3*19)
#define KCW  76      // k-chunk per wave (304/4)
#define NSTEP (T_ + PD)
#define HW   152     // ull words per h/x row (304 floats)
#define BLK_ULL (RB * HW)   // 1216

typedef unsigned long long ull;

// partials: red[m][kc][cc][rr], inner pad 9 (odd stride -> bank spread)
#define RED(m, kc, cc, rr) lds_red[(((m)*4 + (kc))*GC + (cc))*9 + (rr)]

__device__ __forceinline__ void dot4(float& a, const float4& v, const float4& m) {
    a += v.x * m.x; a += v.y * m.y; a += v.z * m.z; a += v.w * m.w;
}

// ---------------------------------------------------------------------------
// Persistent GRU, 2 blocks/CU. Grid (NCB,NBG)=(16,32)=512 blocks, 256 thr.
// Block (cb,bg): rows r0=bg*8..+7, h-cols c0h=cb*19..+18 (57 gate-cols).
// Thread (kc=wave, lane<57): Wih+Whh k-chunk for ONE gate-col = 152 VGPRs.
// Pipeline per step s:
//   top-sync | (s==T_: reload wh) | issue h(s) loads | xs<-xr (x(s+1)) |
//   issue xr<-x(s+2) | hs<-hreg | mid-sync | gh GEMM | red-sync |
//   gates -> h(s+1) store (agent) | drain-sync | arrive | (s+1==T_: reload wi)
//   | gi(s+1) GEMM (hides under peer skew) | spin-wait
// ---------------------------------------------------------------------------
__global__ __launch_bounds__(256, 2) void gru_persist(
    const float* __restrict__ input,   // [B][T][E]
    const int*   __restrict__ target,  // [B][P]
    const float* __restrict__ emb,     // [D][E]
    const float* __restrict__ eWih, const float* __restrict__ eWhh,
    const float* __restrict__ ebih, const float* __restrict__ ebhh,
    const float* __restrict__ dWih, const float* __restrict__ dWhh,
    const float* __restrict__ dbih, const float* __restrict__ dbhh,
    float* hbuf,                       // [2][B*H]
    float* __restrict__ dec_outs,      // [(b*PD+p)*H]
    int* ctr)                          // [NBG*32]
{
    __shared__ float xs[RB][H_];
    __shared__ float hs[RB][H_];
    __shared__ float lds_red[2 * 4 * GC * 9];
    __shared__ float bi_l[GC], bh_l[GC];

    const int tid  = threadIdx.x;
    const int cb   = blockIdx.x;       // 0..15
    const int bg   = blockIdx.y;       // 0..31
    const int r0   = bg * RB;
    const int c0h  = cb * CBH;
    const int kc   = tid >> 6;         // wave id = k-chunk
    const int lane = tid & 63;
    const bool act = lane < GC;
    int* ctrp = ctr + bg * 32;

    float4 wi[19], wh[19];

    auto load_wi = [&](const float* Wih, const float* bih) {
        if (act) {
            int g = lane / CBH, j = lane - (lane / CBH) * CBH;
            const float* pi = Wih + (size_t)(g * H_ + c0h + j) * E_ + kc * KCW;
            #pragma unroll
            for (int q = 0; q < 19; ++q) wi[q] = *(const float4*)(pi + 4 * q);
        }
        if (tid < GC) {
            int g = tid / CBH, j = tid - (tid / CBH) * CBH;
            bi_l[tid] = bih[g * H_ + c0h + j];
        }
    };
    auto load_wh = [&](const float* Whh, const float* bhh) {
        if (act) {
            int g = lane / CBH, j = lane - (lane / CBH) * CBH;
            const float* ph = Whh + (size_t)(g * H_ + c0h + j) * H_ + kc * KCW;
            #pragma unroll
            for (int q = 0; q < 19; ++q) wh[q] = *(const float4*)(ph + 4 * q);
        }
        if (tid < GC) {
            int g = tid / CBH, j = tid - (tid / CBH) * CBH;
            bh_l[tid] = bhh[g * H_ + c0h + j];
        }
    };

    load_wi(eWih, ebih);
    load_wh(eWhh, ebhh);

    // ---- prologue: hs = 0 (=h(0)); xs = x(0) ----
    {
        const ull* xin = (const ull*)input;
        #pragma unroll
        for (int i = 0; i < 5; ++i) {
            int f = tid + 256 * i;
            if (i < 4 || f < BLK_ULL) {
                int rr = f / HW, q = f - (f / HW) * HW;
                ((ull*)xs)[f] = xin[(size_t)(r0 + rr) * T_ * HW + q];
                ((ull*)hs)[f] = 0ull;
            }
        }
    }
    __syncthreads();
    // gi(0)
    if (act) {
        #pragma unroll 4
        for (int rr = 0; rr < RB; ++rr) {
            float a0 = 0.f, a1 = 0.f;
            #pragma unroll
            for (int q = 0; q < 19; ++q) {
                float4 xv = *(const float4*)&xs[rr][kc * KCW + 4 * q];
                if (q & 1) dot4(a1, xv, wi[q]); else dot4(a0, xv, wi[q]);
            }
            RED(0, kc, lane, rr) = a0 + a1;
        }
    }
    // xr <- x(1)
    ull xr[5];
    {
        const ull* xin = (const ull*)input;
        #pragma unroll
        for (int i = 0; i < 5; ++i) {
            int f = tid + 256 * i;
            if (i < 4 || f < BLK_ULL) {
                int rr = f / HW, q = f - (f / HW) * HW;
                xr[i] = xin[((size_t)(r0 + rr) * T_ + 1) * HW + q];
            }
        }
    }

    for (int s = 0; s < NSTEP; ++s) {
        __syncthreads();   // top: RED0(gi s) ready; xs reads of prev gi done
        if (s == T_) load_wh(dWhh, dbhh);

        // ---- issue h(s) loads (MALL) ----
        ull hreg[5];
        if (s > 0) {
            const ull* hsrc = (const ull*)(hbuf + (size_t)(s & 1) * (B_ * H_))
                              + (size_t)r0 * HW;
            #pragma unroll
            for (int i = 0; i < 5; ++i) {
                int f = tid + 256 * i;
                if (i < 4 || f < BLK_ULL)
                    hreg[i] = __hip_atomic_load(hsrc + f, __ATOMIC_RELAXED,
                                                __HIP_MEMORY_SCOPE_AGENT);
            }
        }
        // ---- xs <- xr (= x(s+1)) ----
        if (s + 1 < NSTEP) {
            ull* xd = (ull*)xs;
            #pragma unroll
            for (int i = 0; i < 5; ++i) {
                int f = tid + 256 * i;
                if (i < 4 || f < BLK_ULL) xd[f] = xr[i];
            }
        }
        // ---- issue xr <- x(s+2) ----
        if (s + 2 < NSTEP) {
            if (s + 2 < T_) {
                const ull* xin = (const ull*)input;
                #pragma unroll
                for (int i = 0; i < 5; ++i) {
                    int f = tid + 256 * i;
                    if (i < 4 || f < BLK_ULL) {
                        int rr = f / HW, q = f - (f / HW) * HW;
                        xr[i] = xin[((size_t)(r0 + rr) * T_ + (s + 2)) * HW + q];
                    }
                }
            } else {
                const ull* eb = (const ull*)emb;
                int p2 = s + 2 - T_;
                #pragma unroll
                for (int i = 0; i < 5; ++i) {
                    int f = tid + 256 * i;
                    if (i < 4 || f < BLK_ULL) {
                        int rr = f / HW, q = f - (f / HW) * HW;
                        int tok = (p2 == 0) ? 0 : target[(r0 + rr) * P_ + p2];
                        xr[i] = eb[(size_t)tok * HW + q];
                    }
                }
            }
        }
        // ---- hs <- hreg ----
        if (s > 0) {
            ull* hd = (ull*)hs;
            #pragma unroll
            for (int i = 0; i < 5; ++i) {
                int f = tid + 256 * i;
                if (i < 4 || f < BLK_ULL) hd[f] = hreg[i];
            }
        }
        __syncthreads();   // mid: hs ready

        // ---- gh GEMM: h(s) . Whh ----
        if (act) {
            #pragma unroll 4
            for (int rr = 0; rr < RB; ++rr) {
                float a0 = 0.f, a1 = 0.f;
                #pragma unroll
                for (int q = 0; q < 19; ++q) {
                    float4 hv = *(const float4*)&hs[rr][kc * KCW + 4 * q];
                    if (q & 1) dot4(a1, hv, wh[q]); else dot4(a0, hv, wh[q]);
                }
                RED(1, kc, lane, rr) = a0 + a1;
            }
        }
        __syncthreads();   // red-ready

        // ---- gates -> h(s+1) ----
        float* hdst = hbuf + (size_t)((s + 1) & 1) * (B_ * H_);
        if (tid < RB * CBH) {
            int rr = tid / CBH, j = tid - (tid / CBH) * CBH;
            int col = c0h + j;
            float Gi[3], Gh[3];
            #pragma unroll
            for (int g = 0; g < 3; ++g) {
                int cc = g * CBH + j;
                Gi[g] = RED(0, 0, cc, rr) + RED(0, 1, cc, rr) +
                        RED(0, 2, cc, rr) + RED(0, 3, cc, rr) + bi_l[cc];
                Gh[g] = RED(1, 0, cc, rr) + RED(1, 1, cc, rr) +
                        RED(1, 2, cc, rr) + RED(1, 3, cc, rr) + bh_l[cc];
            }
            float rg = 1.f / (1.f + expf(-(Gi[0] + Gh[0])));
            float zg = 1.f / (1.f + expf(-(Gi[1] + Gh[1])));
            float ng = tanhf(Gi[2] + rg * Gh[2]);
            float hnew = (1.f - zg) * ng + zg * hs[rr][col];
            __hip_atomic_store(&hdst[(size_t)(r0 + rr) * H_ + col], hnew,
                               __ATOMIC_RELAXED, __HIP_MEMORY_SCOPE_AGENT);
            if (s >= T_)
                dec_outs[((size_t)(r0 + rr) * PD + (s - T_)) * H_ + col] = hnew;
        }
        __syncthreads();   // drain: h stores visible; RED0 free

        if (s + 1 < NSTEP) {
            if (tid == 0)
                __hip_atomic_fetch_add(ctrp, 1, __ATOMIC_RELAXED,
                                       __HIP_MEMORY_SCOPE_AGENT);
            if (s + 1 == T_) load_wi(dWih, dbih);
            // ---- gi(s+1): x(s+1) . Wih  (overlaps peer skew) ----
            if (act) {
                #pragma unroll 4
                for (int rr = 0; rr < RB; ++rr) {
                    float a0 = 0.f, a1 = 0.f;
                    #pragma unroll
                    for (int q = 0; q < 19; ++q) {
                        float4 xv = *(const float4*)&xs[rr][kc * KCW + 4 * q];
                        if (q & 1) dot4(a1, xv, wi[q]); else dot4(a0, xv, wi[q]);
                    }
                    RED(0, kc, lane, rr) = a0 + a1;
                }
            }
            if (tid == 0) {
                int tgt = NCB * (s + 1);
                while (__hip_atomic_load(ctrp, __ATOMIC_RELAXED,
                                         __HIP_MEMORY_SCOPE_AGENT) < tgt)
                    __builtin_amdgcn_s_sleep(1);
            }
        }
    }
}

// ---------------------------------------------------------------------------
// logits -> softmax -> (softmax_cal, target_cal, asr_outputs)
// ---------------------------------------------------------------------------
__global__ __launch_bounds__(256) void logits_softmax(
    const float* __restrict__ dec_outs,   // [B*PD][H]
    const float* __restrict__ linW,       // [61][304]
    const float* __restrict__ linb,       // [61]
    const int* __restrict__ target,       // [B][P][1]
    float* __restrict__ out)
{
    __shared__ float wsm[H_][64];   // transposed W
    __shared__ float rs[4][H_];
    const int tid = threadIdx.x;
    const int wv = tid >> 6, l = tid & 63;

    for (int f = tid; f < H_ * 64; f += 256) {
        int k = f >> 6, ll = f & 63;
        wsm[k][ll] = (ll < D_) ? linW[(size_t)ll * H_ + k] : 0.f;
    }
    const int r = blockIdx.x * 4 + wv;
    const float* rowp = dec_outs + (size_t)r * H_;
    for (int k = l; k < H_; k += 64) rs[wv][k] = rowp[k];
    __syncthreads();

    float acc = -1e30f;
    if (l < D_) {
        acc = linb[l];
        #pragma unroll 4
        for (int k = 0; k < H_; ++k) acc += rs[wv][k] * wsm[k][l];
    }
    float m = acc;
    for (int off = 32; off; off >>= 1) m = fmaxf(m, __shfl_xor(m, off));
    float e = (l < D_) ? expf(acc - m) : 0.f;
    float s = e;
    for (int off = 32; off; off >>= 1) s += __shfl_xor(s, off);
    float av = acc; int ai = l;
    for (int off = 32; off; off >>= 1) {
        float ov = __shfl_xor(av, off);
        int oi = __shfl_xor(ai, off);
        if (ov > av || (ov == av && oi < ai)) { av = ov; ai = oi; }
    }
    const int b = r / PD, p = r - (r / PD) * PD;
    const size_t OFF1 = (size_t)B_ * PD * D_;
    const size_t OFF2 = OFF1 + (size_t)B_ * PD;
    if (l < D_)        out[(size_t)r * D_ + l] = e / s;
    else if (l == D_)  out[OFF1 + r] = (float)target[b * P_ + p + 1];
    else if (l == D_ + 1) out[OFF2 + r] = (float)ai;
}

// ---------------------------------------------------------------------------
extern "C" void kernel_launch(void* const* d_in, const int* in_sizes, int n_in,
                              void* d_out, int out_size, void* d_ws, size_t ws_size,
                              hipStream_t stream)
{
    const float* input  = (const float*)d_in[0];
    const int*   target = (const int*)d_in[1];
    const float* eWih = (const float*)d_in[3];
    const float* eWhh = (const float*)d_in[4];
    const float* ebih = (const float*)d_in[5];
    const float* ebhh = (const float*)d_in[6];
    const float* emb  = (const float*)d_in[7];
    const float* dWih = (const float*)d_in[8];
    const float* dWhh = (const float*)d_in[9];
    const float* dbih = (const float*)d_in[10];
    const float* dbhh = (const float*)d_in[11];
    const float* linW = (const float*)d_in[12];
    const float* linb = (const float*)d_in[13];
    float* out = (float*)d_out;

    int*   ctr      = (int*)d_ws;                    // NBG*32 ints (4 KB)
    float* hbuf     = (float*)d_ws + 1024;           // 2 * B*H
    float* dec_outs = hbuf + 2 * (size_t)B_ * H_;    // B*PD*H

    (void)hipMemsetAsync(ctr, 0, 1024 * sizeof(int), stream);

    gru_persist<<<dim3(NCB, NBG), 256, 0, stream>>>(
        input, target, emb,
        eWih, eWhh, ebih, ebhh,
        dWih, dWhh, dbih, dbhh,
        hbuf, dec_outs, ctr);

    logits_softmax<<<dim3(B_ * PD / 4), 256, 0, stream>>>(
        dec_outs, linW, linb, target, out);
}